// Round 4
// baseline (249.078 us; speedup 1.0000x reference)
//
#include <hip/hip_runtime.h>

#define CH 256
#define HH 128
#define WW 128
#define HW (HH * WW)
#define SEGH 16   // rows per vertical segment
#define NSEG 8    // 128 / SEGH

// One block per (b,c) image. 1024 threads (16 waves).
// Dynamic LDS: 64 KiB plane + 8 KiB segment scratch = 72 KiB (2 blocks/CU).
//
// Global traffic: x read ONCE (float4, coalesced), out written ONCE (float4,
// coalesced). All column-order access goes through LDS.
//
//  (a) v[4] = x rows (cold float4); mirror into plane        [plane = x]
//  ---- barrier ----
//  (b) V-threads (col,seg): tmp[16] = column from LDS; segment exit states
//      b2 (tb) / b3 (bt) -> scratch
//  ---- barrier ----
//  (c) fixup: Sin/Tin composed from <=7 summaries; recompute tb/bt seeded
//      with Sin/Tin from tmp; plane[cell] = m2*tb + m3*bt   [plane = vcontrib]
//      (per-cell same-thread overwrite; no extra barrier needed before writes)
//  ---- barrier ----
//  (d) H-threads: constant-decay Kogge-Stone on v[4] (x still in regs),
//      out = m0*lr + m1*rl + plane (ds_read_b128), float4 store.
__global__ __launch_bounds__(1024, 4) void dscan_kernel(
    const float* __restrict__ x,
    const float* __restrict__ decay_logits,
    const float* __restrict__ mix_logits,
    const float* __restrict__ input_scale,
    float* __restrict__ out)
{
    extern __shared__ float smem[];
    float* __restrict__ xs  = smem;           // 16384 floats: plane
    float* __restrict__ scr = smem + HW;      // 2048 floats: b2 | b3

    const int img  = blockIdx.x;              // b*256 + c
    const int c    = img & (CH - 1);
    const int tid  = threadIdx.x;
    const int lane = tid & 63;
    const int wv   = tid >> 6;                // 0..15

    // ---- per-channel params (block-uniform) ----
    const float dl0 = decay_logits[0 * CH + c];
    const float dl1 = decay_logits[1 * CH + c];
    const float dl2 = decay_logits[2 * CH + c];
    const float dl3 = decay_logits[3 * CH + c];
    const float ml0 = mix_logits[0 * CH + c];
    const float ml1 = mix_logits[1 * CH + c];
    const float ml2 = mix_logits[2 * CH + c];
    const float ml3 = mix_logits[3 * CH + c];
    const float il0 = input_scale[0 * CH + c];
    const float il1 = input_scale[1 * CH + c];
    const float il2 = input_scale[2 * CH + c];
    const float il3 = input_scale[3 * CH + c];

    const float d0 = fminf(fmaxf(1.0f / (1.0f + expf(-dl0)), 0.05f), 0.995f);
    const float d1 = fminf(fmaxf(1.0f / (1.0f + expf(-dl1)), 0.05f), 0.995f);
    const float d2 = fminf(fmaxf(1.0f / (1.0f + expf(-dl2)), 0.05f), 0.995f);
    const float d3 = fminf(fmaxf(1.0f / (1.0f + expf(-dl3)), 0.05f), 0.995f);

    const float mmax = fmaxf(fmaxf(ml0, ml1), fmaxf(ml2, ml3));
    const float e0 = expf(ml0 - mmax);
    const float e1 = expf(ml1 - mmax);
    const float e2 = expf(ml2 - mmax);
    const float e3 = expf(ml3 - mmax);
    const float einv = 1.0f / (e0 + e1 + e2 + e3);
    const float m0 = e0 * einv, m1 = e1 * einv, m2 = e2 * einv, m3 = e3 * einv;

    const float sc0 = 1.0f + tanhf(il0);
    const float sc1 = 1.0f + tanhf(il1);
    const float sc2 = 1.0f + tanhf(il2);
    const float sc3 = 1.0f + tanhf(il3);

    const float c0 = (1.0f - d0) * sc0;   // s = d*s + c*x
    const float c1 = (1.0f - d1) * sc1;
    const float c2 = (1.0f - d2) * sc2;
    const float c3 = (1.0f - d3) * sc3;

    // powers of decay for KS steps: q[k] = d^(4*2^k)
    const float d0p4 = (d0 * d0) * (d0 * d0);
    const float d1p4 = (d1 * d1) * (d1 * d1);
    float q0[5], q1[5];
    q0[0] = d0p4; q1[0] = d1p4;
#pragma unroll
    for (int k = 1; k < 5; ++k) { q0[k] = q0[k-1] * q0[k-1]; q1[k] = q1[k-1] * q1[k-1]; }

    float t2 = d2 * d2; t2 = t2 * t2; t2 = t2 * t2; const float d2p16 = t2 * t2;
    float t3 = d3 * d3; t3 = t3 * t3; t3 = t3 * t3; const float d3p16 = t3 * t3;

    const float* __restrict__ xg = x + (size_t)img * HW;
    float* __restrict__ og = out + (size_t)img * HW;

    const int sl    = lane & 31;          // lane within 32-group
    const int half  = lane >> 5;
    const int rbase = (wv << 1) + half;   // 0..31
    const int cb    = sl << 2;            // col base for row access

    // ---- (a) cold read + mirror x into plane ----
    float4 v[4];
#pragma unroll
    for (int it = 0; it < 4; ++it) {
        const int r = (it << 5) + rbase;
        v[it] = *(const float4*)(xg + r * WW + cb);
        *(float4*)(xs + r * WW + cb) = v[it];
    }
    __syncthreads();

    // ---- (b) column segment summaries from LDS ----
    const int col  = tid & (WW - 1);      // 0..127 (wave-uniform seg)
    const int seg  = tid >> 7;            // 0..7
    const int base = seg * SEGH * WW + col;

    float tmp[SEGH];
#pragma unroll
    for (int i = 0; i < SEGH; ++i) tmp[i] = xs[base + i * WW];

    {
        float b2 = 0.0f;
#pragma unroll
        for (int i = 0; i < SEGH; ++i) b2 = fmaf(d2, b2, c2 * tmp[i]);
        float b3 = 0.0f;
#pragma unroll
        for (int i = SEGH - 1; i >= 0; --i) b3 = fmaf(d3, b3, c3 * tmp[i]);
        scr[tid]        = b2;
        scr[1024 + tid] = b3;
    }
    __syncthreads();

    // ---- (c) fixup + overwrite plane with vertical contribution ----
    {
        float Sin = 0.0f;
        for (int j = 0; j < seg; ++j)               // wave-uniform bound
            Sin = fmaf(d2p16, Sin, scr[j * WW + col]);
        float Tin = 0.0f;
        for (int j = NSEG - 1; j > seg; --j)
            Tin = fmaf(d3p16, Tin, scr[1024 + j * WW + col]);

        float vc[SEGH];
        float t = Tin;
#pragma unroll
        for (int i = SEGH - 1; i >= 0; --i) {
            t = fmaf(d3, t, c3 * tmp[i]);           // full bt (seeded)
            vc[i] = m3 * t;
        }
        float s = Sin;
#pragma unroll
        for (int i = 0; i < SEGH; ++i) {
            s = fmaf(d2, s, c2 * tmp[i]);           // full tb (seeded)
            xs[base + i * WW] = fmaf(m2, s, vc[i]);
        }
    }
    __syncthreads();

    // ---- (d) horizontal KS scans + fused combine + float4 store ----
#pragma unroll
    for (int it = 0; it < 4; ++it) {
        const int r = (it << 5) + rbase;
        const float4 xv4 = v[it];
        const float4 vc4 = *(const float4*)(xs + r * WW + cb);  // vertical part

        // local inclusive compose over the 4 elements
        float bL = c0 * xv4.x;
        bL = fmaf(d0, bL, c0 * xv4.y);
        bL = fmaf(d0, bL, c0 * xv4.z);
        bL = fmaf(d0, bL, c0 * xv4.w);
        float bR = c1 * xv4.w;
        bR = fmaf(d1, bR, c1 * xv4.z);
        bR = fmaf(d1, bR, c1 * xv4.y);
        bR = fmaf(d1, bR, c1 * xv4.x);

        // constant-decay Kogge-Stone over 32 lanes, both directions
#pragma unroll
        for (int k = 0; k < 5; ++k) {
            const int off = 1 << k;
            const float bU = __shfl_up(bL, (unsigned)off, 32);
            bL = fmaf(q0[k], (sl >= off) ? bU : 0.0f, bL);
            const float bD = __shfl_down(bR, (unsigned)off, 32);
            bR = fmaf(q1[k], (sl < 32 - off) ? bD : 0.0f, bR);
        }
        // exclusive incoming states
        float EL = __shfl_up(bL, 1u, 32);
        if (sl == 0) EL = 0.0f;
        float ER = __shfl_down(bR, 1u, 32);
        if (sl == 31) ER = 0.0f;

        // recompute elementwise (exact)
        const float l0 = fmaf(d0, EL, c0 * xv4.x);
        const float l1 = fmaf(d0, l0, c0 * xv4.y);
        const float l2 = fmaf(d0, l1, c0 * xv4.z);
        const float l3 = fmaf(d0, l2, c0 * xv4.w);
        const float r3 = fmaf(d1, ER, c1 * xv4.w);
        const float r2 = fmaf(d1, r3, c1 * xv4.z);
        const float r1 = fmaf(d1, r2, c1 * xv4.y);
        const float r0 = fmaf(d1, r1, c1 * xv4.x);

        float4 o4;
        o4.x = vc4.x + fmaf(m0, l0, m1 * r0);
        o4.y = vc4.y + fmaf(m0, l1, m1 * r1);
        o4.z = vc4.z + fmaf(m0, l2, m1 * r2);
        o4.w = vc4.w + fmaf(m0, l3, m1 * r3);
        *(float4*)(og + r * WW + cb) = o4;
    }
}

extern "C" void kernel_launch(void* const* d_in, const int* in_sizes, int n_in,
                              void* d_out, int out_size, void* d_ws, size_t ws_size,
                              hipStream_t stream) {
    const float* x  = (const float*)d_in[0];
    const float* dl = (const float*)d_in[1];
    const float* ml = (const float*)d_in[2];
    const float* is = (const float*)d_in[3];
    float* out = (float*)d_out;

    const size_t lds_bytes = (size_t)(HW + 2048) * sizeof(float);   // 73728

    static bool attr_set = false;   // idempotent host-side attribute; value never changes
    if (!attr_set) {
        (void)hipFuncSetAttribute((const void*)dscan_kernel,
                                  hipFuncAttributeMaxDynamicSharedMemorySize,
                                  (int)lds_bytes);
        attr_set = true;
    }

    dim3 grid(2048), block(1024);
    hipLaunchKernelGGL(dscan_kernel, grid, block, lds_bytes, stream, x, dl, ml, is, out);
}